// Round 24
// baseline (130.736 us; speedup 1.0000x reference)
//
#include <hip/hip_runtime.h>

#define HW 16384      // 128*128
#define CIN 256
#define NCOMP 64
#define MASKC 100     // 4*25
#define NB 4
#define KSTEPS 18     // 576 / 32

typedef __attribute__((ext_vector_type(8))) short bf16x8;
typedef __attribute__((ext_vector_type(4))) float f32x4;
typedef __attribute__((ext_vector_type(4), aligned(4))) float f4u;

__device__ inline ushort f2bf(float f) {
  uint x = __float_as_uint(f);
  return (ushort)((x + 0x7fffu + ((x >> 16) & 1u)) >> 16);
}

// softmax(25) over one subpixel plane + 25->9 tap aggregation + OOB zeroing.
// ldsM layout: [kk*2 + (rr&1)][129] fp32.
__device__ __forceinline__ void softmax_agg(const float* ldsM, int px, int rr,
                                            int h, float* wr9) {
  #pragma unroll
  for (int i = 0; i < 9; i++) wr9[i] = 0.f;

  float m[25], mx = -1e30f;
  #pragma unroll
  for (int kk = 0; kk < 25; kk++) {
    m[kk] = ldsM[(kk * 2 + (rr & 1)) * 129 + px];
    mx = fmaxf(mx, m[kk]);
  }
  float s = 0.f;
  #pragma unroll
  for (int kk = 0; kk < 25; kk++) { m[kk] = __expf(m[kk] - mx); s += m[kk]; }
  float inv = 1.f / s;
  const int r1 = rr >> 1, r2 = rr & 1;
  #pragma unroll
  for (int i = 0; i < 5; i++)
    #pragma unroll
    for (int j = 0; j < 5; j++) {
      const int dy = (r1 + i - 2) >> 1;
      const int dx = (r2 + j - 2) >> 1;
      wr9[(dy + 1) * 3 + (dx + 1)] += m[i * 5 + j] * inv;
    }

  // OOB zeroing (matches reference zero padding of upsampled x)
  #pragma unroll
  for (int dy = -1; dy <= 1; dy++) {
    bool vy = (unsigned)(h + dy) < 128u;
    #pragma unroll
    for (int dx = -1; dx <= 1; dx++) {
      bool vx = (unsigned)(px + dx) < 128u;
      if (!(vy && vx)) wr9[(dy + 1) * 3 + dx + 1] = 0.f;
    }
  }
}

// ---- conv1x1 via MFMA, 1-row blocks, 8 waves: x fp32 -> feat_t(4,16384,64) bf16
// W1b pre-shuffled: afrag(mt,s) = W1b[((mt*8+s)*64 + lane)*8 ..+8)
__global__ __launch_bounds__(512) void conv1x1_mfma(const float* __restrict__ x,
    const ushort* __restrict__ W1b, const float* __restrict__ b1,
    ushort* __restrict__ feat_t) {
  int tid = threadIdx.x, bid = blockIdx.x;    // NB*128 = 512 blocks
  int b = bid >> 7, h = bid & 127;
  int wave = tid >> 6, lane = tid & 63;       // wave 0..7 = 16-px tile
  int l15 = lane & 15, l4 = lane >> 4;

  const float* xb = x + ((size_t)b << 22) + h * 128;
  int n = wave * 16 + l15;                    // pixel within row

  f32x4 acc[4];
  #pragma unroll
  for (int mt = 0; mt < 4; mt++) acc[mt] = (f32x4){0.f, 0.f, 0.f, 0.f};

  #pragma unroll
  for (int s = 0; s < 8; s++) {
    int k0 = s * 32 + l4 * 8;                 // ci base for this lane
    union { bf16x8 v; ushort us[8]; } bf;
    #pragma unroll
    for (int j = 0; j < 8; j++)
      bf.us[j] = f2bf(xb[((size_t)(k0 + j) << 14) + n]);
    #pragma unroll
    for (int mt = 0; mt < 4; mt++) {
      bf16x8 af = *(const bf16x8*)(W1b + (((mt * 8 + s) << 6) + lane) * 8);
      acc[mt] = __builtin_amdgcn_mfma_f32_16x16x32_bf16(af, bf.v, acc[mt], 0, 0, 0);
    }
  }

  ushort* fb = feat_t + (((size_t)(b << 14) + h * 128 + n) << 6);
  #pragma unroll
  for (int mt = 0; mt < 4; mt++) {
    float4 bv = *(const float4*)(b1 + mt * 16 + l4 * 4);
    const float* bvp = (const float*)&bv;
    uint u0 = (uint)f2bf(acc[mt][0] + bvp[0]) | ((uint)f2bf(acc[mt][1] + bvp[1]) << 16);
    uint u1 = (uint)f2bf(acc[mt][2] + bvp[2]) | ((uint)f2bf(acc[mt][3] + bvp[3]) << 16);
    uint2 st; st.x = u0; st.y = u1;
    *(uint2*)(fb + mt * 16 + l4 * 4) = st;
  }
}

// ---- weight prep: fragment-ordered Wr(7,18,64,8) + W1b(4,8,64,8) bf16 ------
__global__ __launch_bounds__(256) void wprep_k(const float* __restrict__ W2,
    const float* __restrict__ W1, ushort* __restrict__ Wr,
    ushort* __restrict__ W1b) {
  int i = blockIdx.x * 256 + threadIdx.x;     // 316*256 = 80896 = 64512+16384
  if (i < 64512) {
    int e = i & 7, lane = (i >> 3) & 63, sm = i >> 9;   // sm in [0,126)
    int s = sm % 18, mt = sm / 18;
    int l15 = lane & 15, l4 = lane >> 4;
    int co = mt * 16 + l15;
    int ci = (s & 1) * 32 + l4 * 8 + e;
    int k = s >> 1;
    float v = (co < MASKC) ? W2[(co * 64 + ci) * 9 + k] : 0.f;
    Wr[i] = f2bf(v);
  } else if (i < 64512 + 16384) {
    int j = i - 64512;
    int e = j & 7, lane = (j >> 3) & 63, sm = j >> 9;   // sm in [0,32)
    int s = sm & 7, mt = sm >> 3;
    int l15 = lane & 15, l4 = lane >> 4;
    int co = mt * 16 + l15;
    int ci = s * 32 + l4 * 8 + e;
    W1b[j] = f2bf(W1[co * 256 + ci]);
  }
}

// ---- FUSED: conv3x3 MFMA + 2-pass softmax + pair-combine (channel-half) ----
// 1024 blocks = (b, h, half). Prologue computed redundantly per half (cheap,
// L2-resident); combine channels partitioned -> zero byte duplication.
__global__ __launch_bounds__(512, 4) void conv3x3_combine(const ushort* __restrict__ feat_t,
    const ushort* __restrict__ Wr, const float* __restrict__ b2,
    const float* __restrict__ x, float* __restrict__ out) {
  __shared__ __align__(16) char smem[50 * 129 * 4 + 64]; // half mask tile / wlds
  int tid = threadIdx.x;
  // XCD-chunked swizzle: 1024 blocks, 8 XCDs, 128 per chunk (bijective)
  int wid = (blockIdx.x & 7) * 128 + (blockIdx.x >> 3);
  int b = wid >> 8, rem = wid & 255;
  int h = rem >> 1, half = rem & 1;           // both halves of (b,h) on same XCD
  int wave = tid >> 6, lane = tid & 63;
  int l15 = lane & 15, l4 = lane >> 4;

  // ---- phase 1: MFMA K-loop; wave -> 16-col tile; B-frag direct from global
  f32x4 acc[7];
  #pragma unroll
  for (int mt = 0; mt < 7; mt++) acc[mt] = (f32x4){0.f, 0.f, 0.f, 0.f};

  int cb = wave * 16;
  const ushort* fb = feat_t + (((size_t)b << 14) << 6);

  #pragma unroll
  for (int s = 0; s < KSTEPS; s++) {
    const int k = s >> 1;
    const int r = k / 3;                      // 0..2
    const int dx = k % 3 - 1;                 // -1..1
    const int ci0 = (s & 1) * 32;

    int hh = h - 1 + r;
    int gc = cb + l15 + dx;
    bf16x8 bfrag = {0, 0, 0, 0, 0, 0, 0, 0};
    if ((unsigned)hh < 128u && (unsigned)gc < 128u)
      bfrag = *(const bf16x8*)(fb + (((size_t)(hh * 128 + gc)) << 6) + ci0 + l4 * 8);

    #pragma unroll
    for (int mt = 0; mt < 7; mt++) {
      bf16x8 afrag = *(const bf16x8*)(Wr + (((mt * 18 + s) << 6) + lane) * 8);
      acc[mt] = __builtin_amdgcn_mfma_f32_16x16x32_bf16(afrag, bfrag, acc[mt], 0, 0, 0);
    }
  }

  float* ldsM = (float*)smem;
  float wr9[9];
  int px = tid & 127, rr = tid >> 7;          // rr = r1*2 + r2

  // ---- phase 2a: dump q=0,1 planes -> [kk*2+q][129]
  #pragma unroll
  for (int mt = 0; mt < 7; mt++) {
    int kkd = mt * 4 + l4;
    if (kkd < 25) {
      int co0 = mt * 16 + l4 * 4;
      ldsM[(kkd * 2 + 0) * 129 + cb + l15] = acc[mt][0] + b2[co0 + 0];
      ldsM[(kkd * 2 + 1) * 129 + cb + l15] = acc[mt][1] + b2[co0 + 1];
    }
  }
  __syncthreads();

  // ---- phase 3a: softmax for rr in {0,1}
  if (rr < 2) softmax_agg(ldsM, px, rr, h, wr9);
  __syncthreads();

  // ---- phase 2b: dump q=2,3 planes
  #pragma unroll
  for (int mt = 0; mt < 7; mt++) {
    int kkd = mt * 4 + l4;
    if (kkd < 25) {
      int co0 = mt * 16 + l4 * 4;
      ldsM[(kkd * 2 + 0) * 129 + cb + l15] = acc[mt][2] + b2[co0 + 2];
      ldsM[(kkd * 2 + 1) * 129 + cb + l15] = acc[mt][3] + b2[co0 + 3];
    }
  }
  __syncthreads();

  // ---- phase 3b: softmax for rr in {2,3}
  if (rr >= 2) softmax_agg(ldsM, px, rr, h, wr9);
  __syncthreads();

  // ---- phase 4: publish weights to LDS [px][37]
  float* wlds = (float*)smem;
  {
    #pragma unroll
    for (int i = 0; i < 9; i++) wlds[px * 37 + rr * 9 + i] = wr9[i];
  }
  __syncthreads();

  // ---- phase 5: pair-combine. thread = (pair pp, ch-eighth); 16 ch each
  // (this block covers channels half*128 .. half*128+127).
  {
    int pp = tid & 63, g = tid >> 6;          // pair 0..63, group 0..7
    int w0 = pp * 2;                          // pixel A; B = w0+1
    float wcA[36], wcB[36];
    #pragma unroll
    for (int i = 0; i < 36; i++) wcA[i] = wlds[w0 * 37 + i];
    #pragma unroll
    for (int i = 0; i < 36; i++) wcB[i] = wlds[(w0 + 1) * 37 + i];

    int cc0 = w0 - 1;
    cc0 = (cc0 < 0) ? 0 : ((cc0 > 124) ? 124 : cc0);
    int off = w0 - 1 - cc0;                   // -1 (w0=0), 0 interior, +1 (w0=126)
    bool o0 = (off == 0), om = (off < 0);

    int ys[3] = {max(h - 1, 0) * 128, h * 128, min(h + 1, 127) * 128};
    int ch0 = half * 128;
    const float* xbase = x + ((size_t)b << 22) + cc0 + (((size_t)ch0) << 14);
    float* ob = out + (((size_t)(b * CIN + ch0)) << 16) + ((2 * h) << 8) + 4 * pp;

    #pragma unroll 2
    for (int cc = 0; cc < 16; cc++) {
      int c = cc * 8 + g;
      const float* xc = xbase + ((size_t)c << 14);
      float a0 = 0.f, a1 = 0.f, a2 = 0.f, a3 = 0.f;
      float b0 = 0.f, b1v = 0.f, b2v = 0.f, b3 = 0.f;
      #pragma unroll
      for (int dy = 0; dy < 3; dy++) {
        f4u f = *(const f4u*)(xc + ys[dy]);
        // align window: A cols = f[off+j], B cols = f[off+1+j]; pad arms are
        // multiplied by OOB-zeroed weights so their value is irrelevant.
        float vA0 = o0 ? f[0] : (om ? 0.f  : f[1]);
        float vA1 = o0 ? f[1] : (om ? f[0] : f[2]);
        float vA2 = o0 ? f[2] : (om ? f[1] : f[3]);
        float vB2 = o0 ? f[3] : (om ? f[2] : 0.f);
        a0 += wcA[0*9+dy*3+0]*vA0 + wcA[0*9+dy*3+1]*vA1 + wcA[0*9+dy*3+2]*vA2;
        a1 += wcA[1*9+dy*3+0]*vA0 + wcA[1*9+dy*3+1]*vA1 + wcA[1*9+dy*3+2]*vA2;
        a2 += wcA[2*9+dy*3+0]*vA0 + wcA[2*9+dy*3+1]*vA1 + wcA[2*9+dy*3+2]*vA2;
        a3 += wcA[3*9+dy*3+0]*vA0 + wcA[3*9+dy*3+1]*vA1 + wcA[3*9+dy*3+2]*vA2;
        b0  += wcB[0*9+dy*3+0]*vA1 + wcB[0*9+dy*3+1]*vA2 + wcB[0*9+dy*3+2]*vB2;
        b1v += wcB[1*9+dy*3+0]*vA1 + wcB[1*9+dy*3+1]*vA2 + wcB[1*9+dy*3+2]*vB2;
        b2v += wcB[2*9+dy*3+0]*vA1 + wcB[2*9+dy*3+1]*vA2 + wcB[2*9+dy*3+2]*vB2;
        b3  += wcB[3*9+dy*3+0]*vA1 + wcB[3*9+dy*3+1]*vA2 + wcB[3*9+dy*3+2]*vB2;
      }
      float* oc = ob + ((size_t)c << 16);
      float4 o0v; o0v.x = a0; o0v.y = a1; o0v.z = b0;  o0v.w = b1v;
      float4 o1v; o1v.x = a2; o1v.y = a3; o1v.z = b2v; o1v.w = b3;
      *(float4*)(oc) = o0v;
      *(float4*)(oc + 256) = o1v;
    }
  }
}

extern "C" void kernel_launch(void* const* d_in, const int* in_sizes, int n_in,
                              void* d_out, int out_size, void* d_ws, size_t ws_size,
                              hipStream_t stream) {
  const float* x  = (const float*)d_in[0];
  const float* W1 = (const float*)d_in[1];
  const float* b1 = (const float*)d_in[2];
  const float* W2 = (const float*)d_in[3];
  const float* b2 = (const float*)d_in[4];
  float* out  = (float*)d_out;

  char* ws = (char*)d_ws;
  ushort* feat_t = (ushort*)ws;                        // 8,388,608 B
  ushort* Wr     = (ushort*)(ws + 8388608);            // 129,024 B
  ushort* W1b    = (ushort*)(ws + 8388608 + 129024);   // 32,768 B

  wprep_k<<<316, 256, 0, stream>>>(W2, W1, Wr, W1b);
  conv1x1_mfma<<<NB * 128, 512, 0, stream>>>(x, W1b, b1, feat_t);
  conv3x3_combine<<<NB * 128 * 2, 512, 0, stream>>>(feat_t, Wr, b2, x, out);
}

// Round 25
// 108.088 us; speedup vs baseline: 1.2095x; 1.2095x over previous
//
#include <hip/hip_runtime.h>

#define HW 16384      // 128*128
#define CIN 256
#define NCOMP 64
#define MASKC 100     // 4*25
#define NB 4
#define KSTEPS 18     // 576 / 32

typedef __attribute__((ext_vector_type(8))) short bf16x8;
typedef __attribute__((ext_vector_type(4))) float f32x4;
typedef __attribute__((ext_vector_type(4), aligned(4))) float f4u;

__device__ inline ushort f2bf(float f) {
  uint x = __float_as_uint(f);
  return (ushort)((x + 0x7fffu + ((x >> 16) & 1u)) >> 16);
}

// softmax(25) over one subpixel plane + 25->9 tap aggregation + OOB zeroing.
// ldsM layout: [kk*2 + (rr&1)][129] fp32.
__device__ __forceinline__ void softmax_agg(const float* ldsM, int px, int rr,
                                            int h, float* wr9) {
  #pragma unroll
  for (int i = 0; i < 9; i++) wr9[i] = 0.f;

  float m[25], mx = -1e30f;
  #pragma unroll
  for (int kk = 0; kk < 25; kk++) {
    m[kk] = ldsM[(kk * 2 + (rr & 1)) * 129 + px];
    mx = fmaxf(mx, m[kk]);
  }
  float s = 0.f;
  #pragma unroll
  for (int kk = 0; kk < 25; kk++) { m[kk] = __expf(m[kk] - mx); s += m[kk]; }
  float inv = 1.f / s;
  const int r1 = rr >> 1, r2 = rr & 1;
  #pragma unroll
  for (int i = 0; i < 5; i++)
    #pragma unroll
    for (int j = 0; j < 5; j++) {
      const int dy = (r1 + i - 2) >> 1;
      const int dx = (r2 + j - 2) >> 1;
      wr9[(dy + 1) * 3 + (dx + 1)] += m[i * 5 + j] * inv;
    }

  // OOB zeroing (matches reference zero padding of upsampled x)
  #pragma unroll
  for (int dy = -1; dy <= 1; dy++) {
    bool vy = (unsigned)(h + dy) < 128u;
    #pragma unroll
    for (int dx = -1; dx <= 1; dx++) {
      bool vx = (unsigned)(px + dx) < 128u;
      if (!(vy && vx)) wr9[(dy + 1) * 3 + dx + 1] = 0.f;
    }
  }
}

// ---- conv1x1 via MFMA, 1-row blocks, 8 waves: x fp32 -> feat_t(4,16384,64) bf16
// W1b pre-shuffled: afrag(mt,s) = W1b[((mt*8+s)*64 + lane)*8 ..+8)
__global__ __launch_bounds__(512) void conv1x1_mfma(const float* __restrict__ x,
    const ushort* __restrict__ W1b, const float* __restrict__ b1,
    ushort* __restrict__ feat_t) {
  int tid = threadIdx.x, bid = blockIdx.x;    // NB*128 = 512 blocks
  int b = bid >> 7, h = bid & 127;
  int wave = tid >> 6, lane = tid & 63;       // wave 0..7 = 16-px tile
  int l15 = lane & 15, l4 = lane >> 4;

  const float* xb = x + ((size_t)b << 22) + h * 128;
  int n = wave * 16 + l15;                    // pixel within row

  f32x4 acc[4];
  #pragma unroll
  for (int mt = 0; mt < 4; mt++) acc[mt] = (f32x4){0.f, 0.f, 0.f, 0.f};

  #pragma unroll
  for (int s = 0; s < 8; s++) {
    int k0 = s * 32 + l4 * 8;                 // ci base for this lane
    union { bf16x8 v; ushort us[8]; } bf;
    #pragma unroll
    for (int j = 0; j < 8; j++)
      bf.us[j] = f2bf(xb[((size_t)(k0 + j) << 14) + n]);
    #pragma unroll
    for (int mt = 0; mt < 4; mt++) {
      bf16x8 af = *(const bf16x8*)(W1b + (((mt * 8 + s) << 6) + lane) * 8);
      acc[mt] = __builtin_amdgcn_mfma_f32_16x16x32_bf16(af, bf.v, acc[mt], 0, 0, 0);
    }
  }

  ushort* fb = feat_t + (((size_t)(b << 14) + h * 128 + n) << 6);
  #pragma unroll
  for (int mt = 0; mt < 4; mt++) {
    float4 bv = *(const float4*)(b1 + mt * 16 + l4 * 4);
    const float* bvp = (const float*)&bv;
    uint u0 = (uint)f2bf(acc[mt][0] + bvp[0]) | ((uint)f2bf(acc[mt][1] + bvp[1]) << 16);
    uint u1 = (uint)f2bf(acc[mt][2] + bvp[2]) | ((uint)f2bf(acc[mt][3] + bvp[3]) << 16);
    uint2 st; st.x = u0; st.y = u1;
    *(uint2*)(fb + mt * 16 + l4 * 4) = st;
  }
}

// ---- weight prep: fragment-ordered Wr(7,18,64,8) + W1b(4,8,64,8) bf16 ------
__global__ __launch_bounds__(256) void wprep_k(const float* __restrict__ W2,
    const float* __restrict__ W1, ushort* __restrict__ Wr,
    ushort* __restrict__ W1b) {
  int i = blockIdx.x * 256 + threadIdx.x;     // 316*256 = 80896 = 64512+16384
  if (i < 64512) {
    int e = i & 7, lane = (i >> 3) & 63, sm = i >> 9;   // sm in [0,126)
    int s = sm % 18, mt = sm / 18;
    int l15 = lane & 15, l4 = lane >> 4;
    int co = mt * 16 + l15;
    int ci = (s & 1) * 32 + l4 * 8 + e;
    int k = s >> 1;
    float v = (co < MASKC) ? W2[(co * 64 + ci) * 9 + k] : 0.f;
    Wr[i] = f2bf(v);
  } else if (i < 64512 + 16384) {
    int j = i - 64512;
    int e = j & 7, lane = (j >> 3) & 63, sm = j >> 9;   // sm in [0,32)
    int s = sm & 7, mt = sm >> 3;
    int l15 = lane & 15, l4 = lane >> 4;
    int co = mt * 16 + l15;
    int ci = s * 32 + l4 * 8 + e;
    W1b[j] = f2bf(W1[co * 256 + ci]);
  }
}

// ---- FUSED: conv3x3 MFMA (feat from L2) + 2-pass softmax + pair-combine ----
// 512 threads, one block per (b,h), XCD-chunked swizzle. LDS 25.9KB.
__global__ __launch_bounds__(512, 4) void conv3x3_combine(const ushort* __restrict__ feat_t,
    const ushort* __restrict__ Wr, const float* __restrict__ b2,
    const float* __restrict__ x, float* __restrict__ out) {
  __shared__ __align__(16) char smem[50 * 129 * 4 + 64]; // half mask tile / wlds
  int tid = threadIdx.x;
  // XCD-chunked swizzle: 512 blocks, 8 XCDs, 64 per chunk (bijective)
  int wid = (blockIdx.x & 7) * 64 + (blockIdx.x >> 3);
  int b = wid >> 7, h = wid & 127;
  int wave = tid >> 6, lane = tid & 63;
  int l15 = lane & 15, l4 = lane >> 4;

  // ---- phase 1: MFMA K-loop; wave -> 16-col tile; B-frag direct from global
  f32x4 acc[7];
  #pragma unroll
  for (int mt = 0; mt < 7; mt++) acc[mt] = (f32x4){0.f, 0.f, 0.f, 0.f};

  int cb = wave * 16;
  const ushort* fb = feat_t + (((size_t)b << 14) << 6);

  #pragma unroll
  for (int s = 0; s < KSTEPS; s++) {
    const int k = s >> 1;
    const int r = k / 3;                      // 0..2
    const int dx = k % 3 - 1;                 // -1..1
    const int ci0 = (s & 1) * 32;

    int hh = h - 1 + r;
    int gc = cb + l15 + dx;
    bf16x8 bfrag = {0, 0, 0, 0, 0, 0, 0, 0};
    if ((unsigned)hh < 128u && (unsigned)gc < 128u)
      bfrag = *(const bf16x8*)(fb + (((size_t)(hh * 128 + gc)) << 6) + ci0 + l4 * 8);

    #pragma unroll
    for (int mt = 0; mt < 7; mt++) {
      bf16x8 afrag = *(const bf16x8*)(Wr + (((mt * 18 + s) << 6) + lane) * 8);
      acc[mt] = __builtin_amdgcn_mfma_f32_16x16x32_bf16(afrag, bfrag, acc[mt], 0, 0, 0);
    }
  }

  float* ldsM = (float*)smem;
  float wr9[9];
  int px = tid & 127, rr = tid >> 7;          // rr = r1*2 + r2

  // ---- phase 2a: dump q=0,1 planes -> [kk*2+q][129]
  #pragma unroll
  for (int mt = 0; mt < 7; mt++) {
    int kkd = mt * 4 + l4;
    if (kkd < 25) {
      int co0 = mt * 16 + l4 * 4;
      ldsM[(kkd * 2 + 0) * 129 + cb + l15] = acc[mt][0] + b2[co0 + 0];
      ldsM[(kkd * 2 + 1) * 129 + cb + l15] = acc[mt][1] + b2[co0 + 1];
    }
  }
  __syncthreads();

  // ---- phase 3a: softmax for rr in {0,1}
  if (rr < 2) softmax_agg(ldsM, px, rr, h, wr9);
  __syncthreads();

  // ---- phase 2b: dump q=2,3 planes
  #pragma unroll
  for (int mt = 0; mt < 7; mt++) {
    int kkd = mt * 4 + l4;
    if (kkd < 25) {
      int co0 = mt * 16 + l4 * 4;
      ldsM[(kkd * 2 + 0) * 129 + cb + l15] = acc[mt][2] + b2[co0 + 2];
      ldsM[(kkd * 2 + 1) * 129 + cb + l15] = acc[mt][3] + b2[co0 + 3];
    }
  }
  __syncthreads();

  // ---- phase 3b: softmax for rr in {2,3}
  if (rr >= 2) softmax_agg(ldsM, px, rr, h, wr9);
  __syncthreads();

  // ---- phase 4: publish weights to LDS [px][37]
  float* wlds = (float*)smem;
  {
    #pragma unroll
    for (int i = 0; i < 9; i++) wlds[px * 37 + rr * 9 + i] = wr9[i];
  }
  __syncthreads();

  // ---- phase 5: pair-combine. thread = (pair pp, ch-eighth); 32 ch each.
  {
    int pp = tid & 63, g = tid >> 6;          // pair 0..63, group 0..7
    int w0 = pp * 2;                          // pixel A; B = w0+1
    float wcA[36], wcB[36];
    #pragma unroll
    for (int i = 0; i < 36; i++) wcA[i] = wlds[w0 * 37 + i];
    #pragma unroll
    for (int i = 0; i < 36; i++) wcB[i] = wlds[(w0 + 1) * 37 + i];

    int cc0 = w0 - 1;
    cc0 = (cc0 < 0) ? 0 : ((cc0 > 124) ? 124 : cc0);
    int off = w0 - 1 - cc0;                   // -1 (w0=0), 0 interior, +1 (w0=126)
    bool o0 = (off == 0), om = (off < 0);

    int ys[3] = {max(h - 1, 0) * 128, h * 128, min(h + 1, 127) * 128};
    const float* xbase = x + ((size_t)b << 22) + cc0;
    float* ob = out + (((size_t)b * CIN) << 16) + ((2 * h) << 8) + 4 * pp;

    #pragma unroll 2
    for (int cc = 0; cc < 32; cc++) {
      int c = cc * 8 + g;
      const float* xc = xbase + ((size_t)c << 14);
      float a0 = 0.f, a1 = 0.f, a2 = 0.f, a3 = 0.f;
      float b0 = 0.f, b1v = 0.f, b2v = 0.f, b3 = 0.f;
      #pragma unroll
      for (int dy = 0; dy < 3; dy++) {
        f4u f = *(const f4u*)(xc + ys[dy]);
        // align window: A cols = f[off+j], B cols = f[off+1+j]; pad arms are
        // multiplied by OOB-zeroed weights so their value is irrelevant.
        float vA0 = o0 ? f[0] : (om ? 0.f  : f[1]);
        float vA1 = o0 ? f[1] : (om ? f[0] : f[2]);
        float vA2 = o0 ? f[2] : (om ? f[1] : f[3]);
        float vB2 = o0 ? f[3] : (om ? f[2] : 0.f);
        a0 += wcA[0*9+dy*3+0]*vA0 + wcA[0*9+dy*3+1]*vA1 + wcA[0*9+dy*3+2]*vA2;
        a1 += wcA[1*9+dy*3+0]*vA0 + wcA[1*9+dy*3+1]*vA1 + wcA[1*9+dy*3+2]*vA2;
        a2 += wcA[2*9+dy*3+0]*vA0 + wcA[2*9+dy*3+1]*vA1 + wcA[2*9+dy*3+2]*vA2;
        a3 += wcA[3*9+dy*3+0]*vA0 + wcA[3*9+dy*3+1]*vA1 + wcA[3*9+dy*3+2]*vA2;
        b0  += wcB[0*9+dy*3+0]*vA1 + wcB[0*9+dy*3+1]*vA2 + wcB[0*9+dy*3+2]*vB2;
        b1v += wcB[1*9+dy*3+0]*vA1 + wcB[1*9+dy*3+1]*vA2 + wcB[1*9+dy*3+2]*vB2;
        b2v += wcB[2*9+dy*3+0]*vA1 + wcB[2*9+dy*3+1]*vA2 + wcB[2*9+dy*3+2]*vB2;
        b3  += wcB[3*9+dy*3+0]*vA1 + wcB[3*9+dy*3+1]*vA2 + wcB[3*9+dy*3+2]*vB2;
      }
      float* oc = ob + ((size_t)c << 16);
      float4 o0v; o0v.x = a0; o0v.y = a1; o0v.z = b0;  o0v.w = b1v;
      float4 o1v; o1v.x = a2; o1v.y = a3; o1v.z = b2v; o1v.w = b3;
      *(float4*)(oc) = o0v;
      *(float4*)(oc + 256) = o1v;
    }
  }
}

extern "C" void kernel_launch(void* const* d_in, const int* in_sizes, int n_in,
                              void* d_out, int out_size, void* d_ws, size_t ws_size,
                              hipStream_t stream) {
  const float* x  = (const float*)d_in[0];
  const float* W1 = (const float*)d_in[1];
  const float* b1 = (const float*)d_in[2];
  const float* W2 = (const float*)d_in[3];
  const float* b2 = (const float*)d_in[4];
  float* out  = (float*)d_out;

  char* ws = (char*)d_ws;
  ushort* feat_t = (ushort*)ws;                        // 8,388,608 B
  ushort* Wr     = (ushort*)(ws + 8388608);            // 129,024 B
  ushort* W1b    = (ushort*)(ws + 8388608 + 129024);   // 32,768 B

  wprep_k<<<316, 256, 0, stream>>>(W2, W1, Wr, W1b);
  conv1x1_mfma<<<NB * 128, 512, 0, stream>>>(x, W1b, b1, feat_t);
  conv3x3_combine<<<NB * 128, 512, 0, stream>>>(feat_t, Wr, b2, x, out);
}